// Round 2
// baseline (5259.324 us; speedup 1.0000x reference)
//
#include <hip/hip_runtime.h>
#include <math.h>

#define TT 2048
#define EE 768
#define HNN 12
#define HSS 64
#define NLAYER 6
#define FFD 3072

constexpr float LN_EPS = 1e-5f;
constexpr float ATT_SCALE = 0.03608439182435161f; // 1/sqrt(768)  (reference divides by sqrt(n_embed)!)

// ---------------------------------------------------------------- copy ----
__global__ __launch_bounds__(256) void copy4_kernel(float4* __restrict__ dst,
                                                    const float4* __restrict__ src, int n4) {
    int i = blockIdx.x * 256 + threadIdx.x;
    if (i < n4) dst[i] = src[i];
}

// ----------------------------------------------------------- layernorm ----
// one block (256 thr) per token; E=768 = 3*256
__global__ __launch_bounds__(256) void ln_kernel(const float* __restrict__ in,
                                                 const float* __restrict__ g,
                                                 const float* __restrict__ b,
                                                 float* __restrict__ out) {
    __shared__ float red[8];
    const int t = blockIdx.x;
    const int tid = threadIdx.x;
    const float* row = in + (size_t)t * EE;
    float v0 = row[tid], v1 = row[tid + 256], v2 = row[tid + 512];
    float s = v0 + v1 + v2;
#pragma unroll
    for (int m = 1; m < 64; m <<= 1) s += __shfl_xor(s, m, 64);
    if ((tid & 63) == 0) red[tid >> 6] = s;
    __syncthreads();
    const float mean = (red[0] + red[1] + red[2] + red[3]) * (1.0f / EE);
    const float d0 = v0 - mean, d1 = v1 - mean, d2 = v2 - mean;
    float qq = d0 * d0 + d1 * d1 + d2 * d2;
#pragma unroll
    for (int m = 1; m < 64; m <<= 1) qq += __shfl_xor(qq, m, 64);
    __syncthreads();
    if ((tid & 63) == 0) red[tid >> 6] = qq;
    __syncthreads();
    const float var = (red[0] + red[1] + red[2] + red[3]) * (1.0f / EE);
    const float rstd = rsqrtf(var + LN_EPS);
    float* orow = out + (size_t)t * EE;
    orow[tid]       = d0 * rstd * g[tid]       + b[tid];
    orow[tid + 256] = d1 * rstd * g[tid + 256] + b[tid + 256];
    orow[tid + 512] = d2 * rstd * g[tid + 512] + b[tid + 512];
}

// ---------------------------------------------------------------- GEMM ----
// C[M,N] = act(A[M,K] @ B[K,N] + bias) (+ resid).  64x64 tile, BK=16,
// 256 threads, 4x4 register blocking.  M,N multiples of 64; K multiple of 16.
template <int ACT, int RES>
__device__ __forceinline__ void gemm_body(const float* __restrict__ A, int lda,
                                          const float* __restrict__ B, int ldb,
                                          const float* __restrict__ bias,
                                          const float* __restrict__ resid,
                                          float* __restrict__ C, int ldc, int K,
                                          int bm, int bn) {
    __shared__ float As[16][68];   // [k][m], +4 pad keeps 16B alignment
    __shared__ float Bs[16][68];   // [k][n]
    const int tid = threadIdx.x;
    const int tx = tid & 15, ty = tid >> 4;
    const int m0 = bm * 64, n0 = bn * 64;
    float acc[4][4] = {{0.f, 0.f, 0.f, 0.f}, {0.f, 0.f, 0.f, 0.f},
                       {0.f, 0.f, 0.f, 0.f}, {0.f, 0.f, 0.f, 0.f}};
    const int ar = tid >> 2, akq = tid & 3;   // A: row ar (0..63), k-quad akq
    const int bk = tid >> 4, bnq = tid & 15;  // B: k row bk (0..15), n-quad bnq
    const float* Ap = A + (size_t)(m0 + ar) * lda + akq * 4;
    const float* Bp = B + (size_t)bk * ldb + n0 + bnq * 4;

    for (int k0 = 0; k0 < K; k0 += 16) {
        const float4 av = *(const float4*)(Ap + k0);
        const float4 bv = *(const float4*)(Bp + (size_t)k0 * ldb);
        __syncthreads();  // previous compute done before we overwrite tiles
        As[akq * 4 + 0][ar] = av.x;
        As[akq * 4 + 1][ar] = av.y;
        As[akq * 4 + 2][ar] = av.z;
        As[akq * 4 + 3][ar] = av.w;
        *(float4*)&Bs[bk][bnq * 4] = bv;
        __syncthreads();
#pragma unroll
        for (int kk = 0; kk < 16; kk++) {
            const float4 a4 = *(const float4*)&As[kk][ty * 4];
            const float4 b4 = *(const float4*)&Bs[kk][tx * 4];
            const float aa[4] = {a4.x, a4.y, a4.z, a4.w};
            const float bb[4] = {b4.x, b4.y, b4.z, b4.w};
#pragma unroll
            for (int i = 0; i < 4; i++)
#pragma unroll
                for (int j = 0; j < 4; j++)
                    acc[i][j] = fmaf(aa[i], bb[j], acc[i][j]);
        }
    }

    const int m = m0 + ty * 4;
    const int n = n0 + tx * 4;
    const float4 bi4 = *(const float4*)(bias + n);
    const float biav[4] = {bi4.x, bi4.y, bi4.z, bi4.w};
#pragma unroll
    for (int i = 0; i < 4; i++) {
        float vr[4];
#pragma unroll
        for (int j = 0; j < 4; j++) {
            float val = acc[i][j] + biav[j];
            if constexpr (ACT == 1)  // exact gelu
                val = 0.5f * val * (1.0f + erff(val * 0.70710678118654752f));
            vr[j] = val;
        }
        float4 outv = make_float4(vr[0], vr[1], vr[2], vr[3]);
        if constexpr (RES == 1) {
            const float4 rv = *(const float4*)(resid + (size_t)(m + i) * ldc + n);
            outv.x += rv.x; outv.y += rv.y; outv.z += rv.z; outv.w += rv.w;
        }
        *(float4*)(C + (size_t)(m + i) * ldc + n) = outv;
    }
}

template <int ACT, int RES>
__global__ __launch_bounds__(256) void gemm_kernel(const float* __restrict__ A, int lda,
                                                   const float* __restrict__ B, int ldb,
                                                   const float* __restrict__ bias,
                                                   const float* __restrict__ resid,
                                                   float* __restrict__ C, int ldc, int K) {
    gemm_body<ACT, RES>(A, lda, B, ldb, bias, resid, C, ldc, K, blockIdx.y, blockIdx.x);
}

// q/k/v: 36 small GEMMs [T,E]x[E,64] selected by blockIdx.z
__global__ __launch_bounds__(256) void qkv_kernel(const float* __restrict__ h,
                                                  const float* __restrict__ wq,
                                                  const float* __restrict__ wk,
                                                  const float* __restrict__ wv,
                                                  const float* __restrict__ bq,
                                                  const float* __restrict__ bk,
                                                  const float* __restrict__ bv,
                                                  float* __restrict__ q,
                                                  float* __restrict__ k,
                                                  float* __restrict__ v) {
    const int z = blockIdx.z;
    const int which = z / HNN, hd = z - which * HNN;
    const float* W; const float* Bi; float* Out;
    if (which == 0)      { W = wq; Bi = bq; Out = q; }
    else if (which == 1) { W = wk; Bi = bk; Out = k; }
    else                 { W = wv; Bi = bv; Out = v; }
    W += (size_t)hd * EE * HSS;
    Bi += (size_t)hd * HSS;
    Out += (size_t)hd * TT * HSS;
    gemm_body<0, 0>(h, EE, W, HSS, Bi, nullptr, Out, HSS, EE, blockIdx.y, 0);
}

// ----------------------------------------------------------- attention ----
// flash-style causal attention: one block per (64-query tile, head).
// q/k/v layout [HN][T][64]; output written head-concat into o[T,E].
// Tiles are 64 rows x 64 head-dims = 1024 float4s -> each of the 256
// threads loads FOUR float4s (row = (tid>>4)+16c, colquad = tid&15), fully
// coalesced (wave = 4 contiguous 256B rows per step).  [R1 fix: previous
// version loaded only head-dims 0..15, leaving LDS rows 16..63 garbage.]
__global__ __launch_bounds__(256) void attn_kernel(const float* __restrict__ qg,
                                                   const float* __restrict__ kg,
                                                   const float* __restrict__ vg,
                                                   float* __restrict__ o) {
    __shared__ float Qs[64][68];   // [d][qi]   (transposed)
    __shared__ float KVs[64][68];  // K phase: [d][kj]; V phase: [kj][d]
    __shared__ float Ps[64][68];   // [kj][qi]
    const int hd = blockIdx.y, qt = blockIdx.x;
    const float* Q = qg + (size_t)hd * TT * HSS;
    const float* K = kg + (size_t)hd * TT * HSS;
    const float* V = vg + (size_t)hd * TT * HSS;
    const int tid = threadIdx.x;
    const int tx = tid & 15, ty = tid >> 4;
    const int rr = tid >> 4;       // row within 16-row group
    const int cc = tid & 15;       // column quad 0..15
#pragma unroll
    for (int c = 0; c < 4; c++) {
        const int row = rr + c * 16;
        const float4 t4 = *(const float4*)(Q + (size_t)(qt * 64 + row) * HSS + cc * 4);
        Qs[cc * 4 + 0][row] = t4.x;
        Qs[cc * 4 + 1][row] = t4.y;
        Qs[cc * 4 + 2][row] = t4.z;
        Qs[cc * 4 + 3][row] = t4.w;
    }
    float m_i[4], l_i[4], oac[4][4];
#pragma unroll
    for (int i = 0; i < 4; i++) {
        m_i[i] = -1e30f;
        l_i[i] = 0.f;
        for (int j = 0; j < 4; j++) oac[i][j] = 0.f;
    }

    for (int kt = 0; kt <= qt; kt++) {
        float4 k4[4];
#pragma unroll
        for (int c = 0; c < 4; c++)
            k4[c] = *(const float4*)(K + (size_t)(kt * 64 + rr + c * 16) * HSS + cc * 4);
        __syncthreads();  // prev iteration's PV reads of KVs/Ps done; Qs visible
#pragma unroll
        for (int c = 0; c < 4; c++) {
            const int row = rr + c * 16;
            KVs[cc * 4 + 0][row] = k4[c].x;
            KVs[cc * 4 + 1][row] = k4[c].y;
            KVs[cc * 4 + 2][row] = k4[c].z;
            KVs[cc * 4 + 3][row] = k4[c].w;
        }
        __syncthreads();
        float sac[4][4] = {{0.f, 0.f, 0.f, 0.f}, {0.f, 0.f, 0.f, 0.f},
                           {0.f, 0.f, 0.f, 0.f}, {0.f, 0.f, 0.f, 0.f}};
#pragma unroll
        for (int s = 0; s < 64; s++) {
            const float4 a4 = *(const float4*)&Qs[s][ty * 4];
            const float4 b4 = *(const float4*)&KVs[s][tx * 4];
            const float aa[4] = {a4.x, a4.y, a4.z, a4.w};
            const float bb[4] = {b4.x, b4.y, b4.z, b4.w};
#pragma unroll
            for (int i = 0; i < 4; i++)
#pragma unroll
                for (int j = 0; j < 4; j++)
                    sac[i][j] = fmaf(aa[i], bb[j], sac[i][j]);
        }
        const bool diag = (kt == qt);
        float alpha[4];
#pragma unroll
        for (int i = 0; i < 4; i++) {
            const int qi = ty * 4 + i;
            float mx = -1e30f;
#pragma unroll
            for (int j = 0; j < 4; j++) {
                float sv = sac[i][j] * ATT_SCALE;
                if (diag && (tx * 4 + j > qi)) sv = -1e30f;
                sac[i][j] = sv;
                mx = fmaxf(mx, sv);
            }
#pragma unroll
            for (int msk = 1; msk < 16; msk <<= 1) mx = fmaxf(mx, __shfl_xor(mx, msk, 64));
            const float nm = fmaxf(m_i[i], mx);
            const float al = __expf(m_i[i] - nm);
            float rs = 0.f;
#pragma unroll
            for (int j = 0; j < 4; j++) {
                const float p = __expf(sac[i][j] - nm);  // masked -> exp(~-1e30) = 0
                sac[i][j] = p;
                rs += p;
            }
#pragma unroll
            for (int msk = 1; msk < 16; msk <<= 1) rs += __shfl_xor(rs, msk, 64);
            l_i[i] = l_i[i] * al + rs;
            m_i[i] = nm;
            alpha[i] = al;
        }
#pragma unroll
        for (int i = 0; i < 4; i++)
#pragma unroll
            for (int j = 0; j < 4; j++) oac[i][j] *= alpha[i];

        float4 v4[4];
#pragma unroll
        for (int c = 0; c < 4; c++)
            v4[c] = *(const float4*)(V + (size_t)(kt * 64 + rr + c * 16) * HSS + cc * 4);
        __syncthreads();  // S-compute reads of KVs done
#pragma unroll
        for (int c = 0; c < 4; c++)
            *(float4*)&KVs[rr + c * 16][cc * 4] = v4[c];  // now holds V tile [kj][d]
#pragma unroll
        for (int i = 0; i < 4; i++)
#pragma unroll
            for (int j = 0; j < 4; j++) Ps[tx * 4 + j][ty * 4 + i] = sac[i][j];
        __syncthreads();
#pragma unroll
        for (int kj = 0; kj < 64; kj++) {
            const float4 a4 = *(const float4*)&Ps[kj][ty * 4];
            const float4 b4 = *(const float4*)&KVs[kj][tx * 4];
            const float aa[4] = {a4.x, a4.y, a4.z, a4.w};
            const float bb[4] = {b4.x, b4.y, b4.z, b4.w};
#pragma unroll
            for (int i = 0; i < 4; i++)
#pragma unroll
                for (int j = 0; j < 4; j++)
                    oac[i][j] = fmaf(aa[i], bb[j], oac[i][j]);
        }
    }

#pragma unroll
    for (int i = 0; i < 4; i++) {
        const float inv = 1.0f / l_i[i];
        const float4 ov = make_float4(oac[i][0] * inv, oac[i][1] * inv,
                                      oac[i][2] * inv, oac[i][3] * inv);
        *(float4*)(o + (size_t)(qt * 64 + ty * 4 + i) * EE + hd * HSS + tx * 4) = ov;
    }
}

// ---------------------------------------------------------------- head ----
__global__ __launch_bounds__(256) void head_kernel(const float* __restrict__ x,
                                                   const float* __restrict__ hw,
                                                   const float* __restrict__ hb,
                                                   float* __restrict__ out) {
    __shared__ float red[8];
    const int t = blockIdx.x, tid = threadIdx.x;
    const float* row = x + (size_t)t * EE;
    float s = row[tid] * hw[tid] + row[tid + 256] * hw[tid + 256] + row[tid + 512] * hw[tid + 512];
#pragma unroll
    for (int m = 1; m < 64; m <<= 1) s += __shfl_xor(s, m, 64);
    if ((tid & 63) == 0) red[tid >> 6] = s;
    __syncthreads();
    if (tid == 0) out[t] = red[0] + red[1] + red[2] + red[3] + hb[0];
}

// -------------------------------------------------------------- launch ----
extern "C" void kernel_launch(void* const* d_in, const int* in_sizes, int n_in,
                              void* d_out, int out_size, void* d_ws, size_t ws_size,
                              hipStream_t stream) {
    const float* idx   = (const float*)d_in[0];
    // d_in[1] = hidden (unused by reference)
    const float* wq    = (const float*)d_in[2];
    const float* bq    = (const float*)d_in[3];
    const float* wk    = (const float*)d_in[4];
    const float* bk    = (const float*)d_in[5];
    const float* wv    = (const float*)d_in[6];
    const float* bv    = (const float*)d_in[7];
    const float* wproj = (const float*)d_in[8];
    const float* bproj = (const float*)d_in[9];
    const float* ln1g  = (const float*)d_in[10];
    const float* ln1b  = (const float*)d_in[11];
    const float* ln2g  = (const float*)d_in[12];
    const float* ln2b  = (const float*)d_in[13];
    const float* w1    = (const float*)d_in[14];
    const float* b1    = (const float*)d_in[15];
    const float* w2    = (const float*)d_in[16];
    const float* b2    = (const float*)d_in[17];
    const float* lnfg  = (const float*)d_in[18];
    const float* lnfb  = (const float*)d_in[19];
    const float* fw1   = (const float*)d_in[20];
    const float* fb1   = (const float*)d_in[21];
    const float* fw2   = (const float*)d_in[22];
    const float* fb2   = (const float*)d_in[23];
    const float* hw    = (const float*)d_in[24];
    const float* hb    = (const float*)d_in[25];
    float* out = (float*)d_out;

    // workspace layout (floats): x,h,q,k,v,o each T*E; ff T*FF  => ~63 MB
    float* x  = (float*)d_ws;
    float* h  = x + (size_t)TT * EE;
    float* q  = h + (size_t)TT * EE;
    float* k  = q + (size_t)TT * EE;
    float* v  = k + (size_t)TT * EE;
    float* o  = v + (size_t)TT * EE;
    float* ff = o + (size_t)TT * EE;

    // only batch 3 contributes to the output (logits[-1]; no cross-batch mixing)
    copy4_kernel<<<dim3((TT * EE / 4 + 255) / 256), dim3(256), 0, stream>>>(
        (float4*)x, (const float4*)(idx + (size_t)3 * TT * EE), TT * EE / 4);

    for (int l = 0; l < NLAYER; l++) {
        ln_kernel<<<dim3(TT), dim3(256), 0, stream>>>(x, ln1g + l * EE, ln1b + l * EE, h);
        qkv_kernel<<<dim3(1, TT / 64, 36), dim3(256), 0, stream>>>(
            h,
            wq + (size_t)l * HNN * EE * HSS, wk + (size_t)l * HNN * EE * HSS,
            wv + (size_t)l * HNN * EE * HSS,
            bq + (size_t)l * HNN * HSS, bk + (size_t)l * HNN * HSS,
            bv + (size_t)l * HNN * HSS,
            q, k, v);
        attn_kernel<<<dim3(TT / 64, HNN), dim3(256), 0, stream>>>(q, k, v, o);
        gemm_kernel<0, 1><<<dim3(EE / 64, TT / 64), dim3(256), 0, stream>>>(
            o, EE, wproj + (size_t)l * EE * EE, EE, bproj + (size_t)l * EE, x, x, EE, EE);
        ln_kernel<<<dim3(TT), dim3(256), 0, stream>>>(x, ln2g + l * EE, ln2b + l * EE, h);
        gemm_kernel<1, 0><<<dim3(FFD / 64, TT / 64), dim3(256), 0, stream>>>(
            h, EE, w1 + (size_t)l * EE * FFD, FFD, b1 + (size_t)l * FFD, nullptr, ff, FFD, EE);
        gemm_kernel<0, 1><<<dim3(EE / 64, TT / 64), dim3(256), 0, stream>>>(
            ff, FFD, w2 + (size_t)l * FFD * EE, EE, b2 + (size_t)l * EE, x, x, EE, FFD);
    }
    ln_kernel<<<dim3(TT), dim3(256), 0, stream>>>(x, lnfg, lnfb, h);
    gemm_kernel<1, 0><<<dim3(FFD / 64, TT / 64), dim3(256), 0, stream>>>(
        h, EE, fw1, FFD, fb1, nullptr, ff, FFD, EE);
    gemm_kernel<0, 0><<<dim3(EE / 64, TT / 64), dim3(256), 0, stream>>>(
        ff, FFD, fw2, EE, fb2, nullptr, h, EE, FFD);
    head_kernel<<<dim3(TT), dim3(256), 0, stream>>>(h, hw, hb, out);
}

// Round 4
// 2079.881 us; speedup vs baseline: 2.5287x; 2.5287x over previous
//
#include <hip/hip_runtime.h>
#include <math.h>

#define TT 2048
#define EE 768
#define HNN 12
#define HSS 64
#define NLAYER 6
#define FFD 3072
#define QKVN 2304

constexpr float LN_EPS = 1e-5f;
constexpr float ATT_SCALE = 0.03608439182435161f; // 1/sqrt(768) (reference divides by sqrt(n_embed))

typedef __attribute__((ext_vector_type(8))) short bf16x8;
typedef __attribute__((ext_vector_type(4))) float f32x4;

__device__ __forceinline__ ushort f2bf(float f) {
    union { float f; uint u; } c; c.f = f;
    const uint u = c.u;
    return (ushort)((u + 0x7fffu + ((u >> 16) & 1u)) >> 16);
}

__device__ __forceinline__ void gload16(const void* g, void* l) {
    __builtin_amdgcn_global_load_lds((const __attribute__((address_space(1))) void*)g,
                                     (__attribute__((address_space(3))) void*)l, 16, 0, 0);
}

// ---------------------------------------------------------------- copy ----
__global__ __launch_bounds__(256) void copy4_kernel(float4* __restrict__ dst,
                                                    const float4* __restrict__ src, int n4) {
    int i = blockIdx.x * 256 + threadIdx.x;
    if (i < n4) dst[i] = src[i];
}

// ----------------------------------------------------------- layernorm ----
// one block (256 thr) per token; E=768 = 3*256.  fp32 in -> bf16 out.
__global__ __launch_bounds__(256) void ln_kernel(const float* __restrict__ in,
                                                 const float* __restrict__ g,
                                                 const float* __restrict__ b,
                                                 ushort* __restrict__ out) {
    __shared__ float red[8];
    const int t = blockIdx.x;
    const int tid = threadIdx.x;
    const float* row = in + (size_t)t * EE;
    float v0 = row[tid], v1 = row[tid + 256], v2 = row[tid + 512];
    float s = v0 + v1 + v2;
#pragma unroll
    for (int m = 1; m < 64; m <<= 1) s += __shfl_xor(s, m, 64);
    if ((tid & 63) == 0) red[tid >> 6] = s;
    __syncthreads();
    const float mean = (red[0] + red[1] + red[2] + red[3]) * (1.0f / EE);
    const float d0 = v0 - mean, d1 = v1 - mean, d2 = v2 - mean;
    float qq = d0 * d0 + d1 * d1 + d2 * d2;
#pragma unroll
    for (int m = 1; m < 64; m <<= 1) qq += __shfl_xor(qq, m, 64);
    __syncthreads();
    if ((tid & 63) == 0) red[tid >> 6] = qq;
    __syncthreads();
    const float var = (red[0] + red[1] + red[2] + red[3]) * (1.0f / EE);
    const float rstd = rsqrtf(var + LN_EPS);
    ushort* orow = out + (size_t)t * EE;
    orow[tid]       = f2bf(d0 * rstd * g[tid]       + b[tid]);
    orow[tid + 256] = f2bf(d1 * rstd * g[tid + 256] + b[tid + 256]);
    orow[tid + 512] = f2bf(d2 * rstd * g[tid + 512] + b[tid + 512]);
}

// --------------------------------------------------- weight pack (fp32->bf16^T)
// dst[n][k] (bf16, row stride dld) = src[k][n] (fp32, row stride sld), 64x64 tile
__device__ __forceinline__ void transpose64(const float* __restrict__ src, int sld,
                                            ushort* __restrict__ dst, int dld,
                                            int k0, int n0, int tid) {
    __shared__ float t[64][68];
#pragma unroll
    for (int p = 0; p < 4; p++) {
        const int kr = p * 16 + (tid >> 4);
        *(float4*)&t[kr][(tid & 15) * 4] =
            *(const float4*)&src[(size_t)(k0 + kr) * sld + n0 + (tid & 15) * 4];
    }
    __syncthreads();
#pragma unroll
    for (int q = 0; q < 2; q++) {
        const int nl = q * 32 + (tid >> 3);
        const int kc = (tid & 7) * 8;
        ushort v[8];
#pragma unroll
        for (int j = 0; j < 8; j++) v[j] = f2bf(t[kc + j][nl]);
        uint4 o;
        o.x = (uint)v[0] | ((uint)v[1] << 16);
        o.y = (uint)v[2] | ((uint)v[3] << 16);
        o.z = (uint)v[4] | ((uint)v[5] << 16);
        o.w = (uint)v[6] | ((uint)v[7] << 16);
        *(uint4*)&dst[(size_t)(n0 + nl) * dld + k0 + kc] = o;
    }
}

__global__ __launch_bounds__(256) void pack_t_kernel(const float* __restrict__ src, int sld,
                                                     ushort* __restrict__ dst, int dld) {
    transpose64(src, sld, dst, dld, blockIdx.x * 64, blockIdx.y * 64, threadIdx.x);
}

// qkv weights [HN][E][HS] (3 tensors) -> Wqkv_t[2304][768] bf16 (row n = which*768+h*64+s)
__global__ __launch_bounds__(256) void pack_qkv_kernel(const float* __restrict__ wq,
                                                       const float* __restrict__ wk,
                                                       const float* __restrict__ wv,
                                                       ushort* __restrict__ dst) {
    const int z = blockIdx.z;
    const int which = z / HNN, hd = z % HNN;
    const float* src = (which == 0 ? wq : which == 1 ? wk : wv) + (size_t)hd * EE * HSS;
    ushort* d = dst + (size_t)(which * EE + hd * HSS) * EE;
    transpose64(src, HSS, d, EE, blockIdx.x * 64, 0, threadIdx.x);
}

// ---------------------------------------------------------- bf16 GEMM ----
// C[M,N] = epi(A[M,K] @ Bt[N,K]^T + bias).  128x128 tile, BK=32, 4 waves
// each computing 64x64 via 4x4 grid of 16x16x32 bf16 MFMAs.
// A,Bt row-major bf16.  global_load_lds width=16 staging (wave-uniform LDS base).
// EPI: 0 = qkv (bf16 out, piecewise bias b0/b1/b2)
//      1 = residual add (outF += acc + bias)
//      2 = gelu -> bf16 out
//      3 = plain fp32 out
template <int EPI>
__global__ __launch_bounds__(256) void gemm_bf16(const ushort* __restrict__ A,
                                                 const ushort* __restrict__ Bt,
                                                 const float* __restrict__ b0,
                                                 const float* __restrict__ b1,
                                                 const float* __restrict__ b2,
                                                 float* __restrict__ outF,
                                                 ushort* __restrict__ outB,
                                                 int N, int K) {
    __shared__ ushort Al[128 * 32];
    __shared__ ushort Bl[128 * 32];
    const int tid = threadIdx.x;
    const int wave = tid >> 6, lane = tid & 63;
    const int wm = wave >> 1, wn = wave & 1;
    const int l15 = lane & 15, q4 = lane >> 4;
    const int m0 = blockIdx.y * 128, n0 = blockIdx.x * 128;

    const ushort* Ag0 = A + (size_t)(m0 + wave * 16 + (lane >> 2)) * K + (lane & 3) * 8;
    const ushort* Ag1 = Ag0 + (size_t)64 * K;
    const ushort* Bg0 = Bt + (size_t)(n0 + wave * 16 + (lane >> 2)) * K + (lane & 3) * 8;
    const ushort* Bg1 = Bg0 + (size_t)64 * K;
    ushort* Al0 = &Al[(wave * 16) * 32];
    ushort* Al1 = &Al[(64 + wave * 16) * 32];
    ushort* Bl0 = &Bl[(wave * 16) * 32];
    ushort* Bl1 = &Bl[(64 + wave * 16) * 32];

    f32x4 acc[4][4];
#pragma unroll
    for (int i = 0; i < 4; i++)
#pragma unroll
        for (int j = 0; j < 4; j++) acc[i][j] = (f32x4){0.f, 0.f, 0.f, 0.f};

    for (int k0 = 0; k0 < K; k0 += 32) {
        __syncthreads();  // prior MFMA reads of LDS complete
        gload16(Ag0 + k0, Al0);
        gload16(Ag1 + k0, Al1);
        gload16(Bg0 + k0, Bl0);
        gload16(Bg1 + k0, Bl1);
        __syncthreads();  // compiler drains vmcnt before s_barrier
        bf16x8 af[4], bfr[4];
#pragma unroll
        for (int i = 0; i < 4; i++)
            af[i] = *(const bf16x8*)&Al[(wm * 64 + i * 16 + l15) * 32 + q4 * 8];
#pragma unroll
        for (int j = 0; j < 4; j++)
            bfr[j] = *(const bf16x8*)&Bl[(wn * 64 + j * 16 + l15) * 32 + q4 * 8];
#pragma unroll
        for (int i = 0; i < 4; i++)
#pragma unroll
            for (int j = 0; j < 4; j++)
                acc[i][j] = __builtin_amdgcn_mfma_f32_16x16x32_bf16(af[i], bfr[j], acc[i][j], 0, 0, 0);
    }

#pragma unroll
    for (int i = 0; i < 4; i++) {
        const int row = m0 + wm * 64 + i * 16 + q4 * 4;
#pragma unroll
        for (int j = 0; j < 4; j++) {
            const int col = n0 + wn * 64 + j * 16 + l15;
            float bias;
            if constexpr (EPI == 0)
                bias = (col < 768) ? b0[col] : (col < 1536 ? b1[col - 768] : b2[col - 1536]);
            else
                bias = b0[col];
#pragma unroll
            for (int r = 0; r < 4; r++) {
                const float v = acc[i][j][r] + bias;
                const size_t idx = (size_t)(row + r) * N + col;
                if constexpr (EPI == 0) {
                    outB[idx] = f2bf(v);
                } else if constexpr (EPI == 1) {
                    outF[idx] += v;
                } else if constexpr (EPI == 2) {
                    outB[idx] = f2bf(0.5f * v * (1.0f + erff(v * 0.70710678118654752f)));
                } else {
                    outF[idx] = v;
                }
            }
        }
    }
}

// ----------------------------------------------------- MFMA attention ----
// flash-style causal attention, bf16 MFMA.  qkv [T][2304] bf16 (q|k|v each
// [T][768] head-major h*64+d).  One block per (64-q-tile, head); wave w owns
// q rows w*16..w*16+15.  LDS rows padded to 72 bf16 (144B).
// STAGING [R3 fix]: a 64x64 bf16 tile is 128 B/row = 8 uint4/row; with 256
// threads each thread moves TWO uint4s (rw = tid>>3 gives 8 thr/row, two
// 32-row passes).  Previous version staged only half the tile, leaving
// uninitialized LDS (arbitrary garbage incl. inf patterns) in the fragments
// -> NaN.
__global__ __launch_bounds__(256) void attn_mfma(const ushort* __restrict__ qkv,
                                                 ushort* __restrict__ o_bf) {
    __shared__ ushort Qs[64 * 72];
    __shared__ ushort Ks[64 * 72];
    __shared__ ushort Ps[64 * 72];
    __shared__ ushort VT[64 * 72];  // V transposed: [d][key]
    const int qt = blockIdx.x, hd = blockIdx.y;
    const int tid = threadIdx.x;
    const int wave = tid >> 6, lane = tid & 63;
    const int l15 = lane & 15, q4 = lane >> 4;
    const int rw = tid >> 3;      // 0..31: row within 32-row pass
    const int ch = tid & 7;       // 0..7: 16B chunk within 128B row

#pragma unroll
    for (int p = 0; p < 2; p++) {
        const int row = rw + p * 32;
        *(uint4*)&Qs[row * 72 + ch * 8] =
            *(const uint4*)&qkv[(size_t)(qt * 64 + row) * QKVN + hd * 64 + ch * 8];
    }

    float m_i[4] = {-1e30f, -1e30f, -1e30f, -1e30f};
    float l_i[4] = {0.f, 0.f, 0.f, 0.f};
    f32x4 oacc[4];
#pragma unroll
    for (int n = 0; n < 4; n++) oacc[n] = (f32x4){0.f, 0.f, 0.f, 0.f};

    for (int kt = 0; kt <= qt; kt++) {
        __syncthreads();  // prev PV reads of VT/Ps done (also covers Q staging)
#pragma unroll
        for (int p = 0; p < 2; p++) {
            const int row = rw + p * 32;
            *(uint4*)&Ks[row * 72 + ch * 8] =
                *(const uint4*)&qkv[(size_t)(kt * 64 + row) * QKVN + 768 + hd * 64 + ch * 8];
            const uint4 w = *(const uint4*)&qkv[(size_t)(kt * 64 + row) * QKVN + 1536 + hd * 64 + ch * 8];
            const int d0 = ch * 8;
            VT[(d0 + 0) * 72 + row] = (ushort)(w.x & 0xffff);
            VT[(d0 + 1) * 72 + row] = (ushort)(w.x >> 16);
            VT[(d0 + 2) * 72 + row] = (ushort)(w.y & 0xffff);
            VT[(d0 + 3) * 72 + row] = (ushort)(w.y >> 16);
            VT[(d0 + 4) * 72 + row] = (ushort)(w.z & 0xffff);
            VT[(d0 + 5) * 72 + row] = (ushort)(w.z >> 16);
            VT[(d0 + 6) * 72 + row] = (ushort)(w.w & 0xffff);
            VT[(d0 + 7) * 72 + row] = (ushort)(w.w >> 16);
        }
        __syncthreads();

        // S = Q K^T for this wave's 16 q-rows (4 key-tiles of 16)
        f32x4 s[4];
#pragma unroll
        for (int n = 0; n < 4; n++) {
            f32x4 a = (f32x4){0.f, 0.f, 0.f, 0.f};
#pragma unroll
            for (int kb = 0; kb < 2; kb++) {
                const bf16x8 qa = *(const bf16x8*)&Qs[(wave * 16 + l15) * 72 + kb * 32 + q4 * 8];
                const bf16x8 kf = *(const bf16x8*)&Ks[(n * 16 + l15) * 72 + kb * 32 + q4 * 8];
                a = __builtin_amdgcn_mfma_f32_16x16x32_bf16(qa, kf, a, 0, 0, 0);
            }
            s[n] = a;
        }

        const bool diag = (kt == qt);
        float alpha[4];
#pragma unroll
        for (int r = 0; r < 4; r++) {
            const int qrow = wave * 16 + q4 * 4 + r;  // local within 64-q tile
            float sv[4];
            float mx = -1e30f;
#pragma unroll
            for (int n = 0; n < 4; n++) {
                float x = s[n][r] * ATT_SCALE;
                if (diag && (n * 16 + l15) > qrow) x = -1e30f;
                sv[n] = x;
                mx = fmaxf(mx, x);
            }
#pragma unroll
            for (int msk = 1; msk < 16; msk <<= 1) mx = fmaxf(mx, __shfl_xor(mx, msk, 64));
            const float nm = fmaxf(m_i[r], mx);
            const float al = __expf(m_i[r] - nm);
            float rs = 0.f;
            float pe[4];
#pragma unroll
            for (int n = 0; n < 4; n++) {
                pe[n] = __expf(sv[n] - nm);
                rs += pe[n];
            }
#pragma unroll
            for (int msk = 1; msk < 16; msk <<= 1) rs += __shfl_xor(rs, msk, 64);
            l_i[r] = l_i[r] * al + rs;
            m_i[r] = nm;
            alpha[r] = al;
            // P in A-operand layout: Ps[qrow][key]
#pragma unroll
            for (int n = 0; n < 4; n++)
                Ps[qrow * 72 + n * 16 + l15] = f2bf(pe[n]);
        }
#pragma unroll
        for (int n = 0; n < 4; n++) {
            oacc[n][0] *= alpha[0];
            oacc[n][1] *= alpha[1];
            oacc[n][2] *= alpha[2];
            oacc[n][3] *= alpha[3];
        }
        __syncthreads();  // Ps/VT visible to all lanes

        // O += P V   (4 d-tiles of 16)
#pragma unroll
        for (int n = 0; n < 4; n++) {
#pragma unroll
            for (int kb = 0; kb < 2; kb++) {
                const bf16x8 pa = *(const bf16x8*)&Ps[(wave * 16 + l15) * 72 + kb * 32 + q4 * 8];
                const bf16x8 vb = *(const bf16x8*)&VT[(n * 16 + l15) * 72 + kb * 32 + q4 * 8];
                oacc[n] = __builtin_amdgcn_mfma_f32_16x16x32_bf16(pa, vb, oacc[n], 0, 0, 0);
            }
        }
    }

#pragma unroll
    for (int n = 0; n < 4; n++)
#pragma unroll
        for (int r = 0; r < 4; r++) {
            const float v = oacc[n][r] / l_i[r];
            o_bf[(size_t)(qt * 64 + wave * 16 + q4 * 4 + r) * EE + hd * 64 + n * 16 + l15] = f2bf(v);
        }
}

// ---------------------------------------------------------------- head ----
__global__ __launch_bounds__(256) void head_kernel(const float* __restrict__ x,
                                                   const float* __restrict__ hw,
                                                   const float* __restrict__ hb,
                                                   float* __restrict__ out) {
    __shared__ float red[8];
    const int t = blockIdx.x, tid = threadIdx.x;
    const float* row = x + (size_t)t * EE;
    float s = row[tid] * hw[tid] + row[tid + 256] * hw[tid + 256] + row[tid + 512] * hw[tid + 512];
#pragma unroll
    for (int m = 1; m < 64; m <<= 1) s += __shfl_xor(s, m, 64);
    if ((tid & 63) == 0) red[tid >> 6] = s;
    __syncthreads();
    if (tid == 0) out[t] = red[0] + red[1] + red[2] + red[3] + hb[0];
}

// -------------------------------------------------------------- launch ----
extern "C" void kernel_launch(void* const* d_in, const int* in_sizes, int n_in,
                              void* d_out, int out_size, void* d_ws, size_t ws_size,
                              hipStream_t stream) {
    const float* idx   = (const float*)d_in[0];
    const float* wq    = (const float*)d_in[2];
    const float* bq    = (const float*)d_in[3];
    const float* wk    = (const float*)d_in[4];
    const float* bk    = (const float*)d_in[5];
    const float* wv    = (const float*)d_in[6];
    const float* bv    = (const float*)d_in[7];
    const float* wproj = (const float*)d_in[8];
    const float* bproj = (const float*)d_in[9];
    const float* ln1g  = (const float*)d_in[10];
    const float* ln1b  = (const float*)d_in[11];
    const float* ln2g  = (const float*)d_in[12];
    const float* ln2b  = (const float*)d_in[13];
    const float* w1    = (const float*)d_in[14];
    const float* b1    = (const float*)d_in[15];
    const float* w2    = (const float*)d_in[16];
    const float* b2    = (const float*)d_in[17];
    const float* lnfg  = (const float*)d_in[18];
    const float* lnfb  = (const float*)d_in[19];
    const float* fw1   = (const float*)d_in[20];
    const float* fb1   = (const float*)d_in[21];
    const float* fw2   = (const float*)d_in[22];
    const float* fb2   = (const float*)d_in[23];
    const float* hw    = (const float*)d_in[24];
    const float* hb    = (const float*)d_in[25];
    float* out = (float*)d_out;

    // ---- workspace carve (~47 MB) ----
    char* p = (char*)d_ws;
    auto alloc = [&](size_t bytes) { void* r = (void*)p; p += (bytes + 255) & ~(size_t)255; return r; };
    float*  x     = (float*)alloc((size_t)TT * EE * 4);
    ushort* h_bf  = (ushort*)alloc((size_t)TT * EE * 2);
    ushort* qkvb  = (ushort*)alloc((size_t)TT * QKVN * 2);
    ushort* o_bf  = (ushort*)alloc((size_t)TT * EE * 2);
    ushort* ffb   = (ushort*)alloc((size_t)TT * FFD * 2);
    ushort* Wqkv  = (ushort*)alloc((size_t)QKVN * EE * 2);
    ushort* Wproj = (ushort*)alloc((size_t)EE * EE * 2);
    ushort* W1t   = (ushort*)alloc((size_t)FFD * EE * 2);
    ushort* W2t   = (ushort*)alloc((size_t)EE * FFD * 2);

    // only batch 3 contributes to the output (logits[-1]; no cross-batch mixing)
    copy4_kernel<<<dim3((TT * EE / 4 + 255) / 256), dim3(256), 0, stream>>>(
        (float4*)x, (const float4*)(idx + (size_t)3 * TT * EE), TT * EE / 4);

    for (int l = 0; l < NLAYER; l++) {
        const size_t lw = (size_t)l;
        pack_qkv_kernel<<<dim3(12, 1, 36), dim3(256), 0, stream>>>(
            wq + lw * HNN * EE * HSS, wk + lw * HNN * EE * HSS, wv + lw * HNN * EE * HSS, Wqkv);
        pack_t_kernel<<<dim3(12, 12), dim3(256), 0, stream>>>(wproj + lw * EE * EE, EE, Wproj, EE);
        pack_t_kernel<<<dim3(12, 48), dim3(256), 0, stream>>>(w1 + lw * EE * FFD, FFD, W1t, EE);
        pack_t_kernel<<<dim3(48, 12), dim3(256), 0, stream>>>(w2 + lw * FFD * EE, EE, W2t, FFD);

        ln_kernel<<<dim3(TT), dim3(256), 0, stream>>>(x, ln1g + lw * EE, ln1b + lw * EE, h_bf);
        gemm_bf16<0><<<dim3(QKVN / 128, TT / 128), dim3(256), 0, stream>>>(
            h_bf, Wqkv, bq + lw * EE, bk + lw * EE, bv + lw * EE, nullptr, qkvb, QKVN, EE);
        attn_mfma<<<dim3(TT / 64, HNN), dim3(256), 0, stream>>>(qkvb, o_bf);
        gemm_bf16<1><<<dim3(EE / 128, TT / 128), dim3(256), 0, stream>>>(
            o_bf, Wproj, bproj + lw * EE, nullptr, nullptr, x, nullptr, EE, EE);
        ln_kernel<<<dim3(TT), dim3(256), 0, stream>>>(x, ln2g + lw * EE, ln2b + lw * EE, h_bf);
        gemm_bf16<2><<<dim3(FFD / 128, TT / 128), dim3(256), 0, stream>>>(
            h_bf, W1t, b1 + lw * FFD, nullptr, nullptr, nullptr, ffb, FFD, EE);
        gemm_bf16<1><<<dim3(EE / 128, TT / 128), dim3(256), 0, stream>>>(
            ffb, W2t, b2 + lw * EE, nullptr, nullptr, x, nullptr, EE, FFD);
    }

    ln_kernel<<<dim3(TT), dim3(256), 0, stream>>>(x, lnfg, lnfb, h_bf);
    pack_t_kernel<<<dim3(12, 48), dim3(256), 0, stream>>>(fw1, FFD, W1t, EE);
    pack_t_kernel<<<dim3(48, 12), dim3(256), 0, stream>>>(fw2, EE, W2t, FFD);
    gemm_bf16<2><<<dim3(FFD / 128, TT / 128), dim3(256), 0, stream>>>(
        h_bf, W1t, fb1, nullptr, nullptr, nullptr, ffb, FFD, EE);
    gemm_bf16<3><<<dim3(EE / 128, TT / 128), dim3(256), 0, stream>>>(
        ffb, W2t, fb2, nullptr, nullptr, x, nullptr, EE, FFD);
    head_kernel<<<dim3(TT), dim3(256), 0, stream>>>(x, hw, hb, out);
}